// Round 2
// baseline (448.467 us; speedup 1.0000x reference)
//
#include <hip/hip_runtime.h>
#include <hip/hip_bf16.h>

#define DIVUP(a, b) (((a) + (b) - 1) / (b))

typedef __attribute__((ext_vector_type(8))) short bf16x8;
typedef __attribute__((ext_vector_type(4))) float f32x4;

// ---------- helpers ----------
__device__ __forceinline__ float bf2f(unsigned short u) {
    union { unsigned int i; float f; } v;
    v.i = ((unsigned int)u) << 16;
    return v.f;
}
__device__ __forceinline__ unsigned short f2bfu(float x) {
    return __hip_bfloat16_raw(__float2bfloat16(x)).x;   // RNE
}
__device__ __forceinline__ float gload(const void* p, int i, int isbf) {
    return isbf ? bf2f(((const unsigned short*)p)[i]) : ((const float*)p)[i];
}

// ---------- dtype detection (round-1 note; f32 vs bf16 inputs) ----------
__global__ void __launch_bounds__(256) detect_dtype(const void* __restrict__ feat,
                                                    int* __restrict__ flag) {
    __shared__ int cnt;
    if (threadIdx.x == 0) cnt = 0;
    __syncthreads();
    const unsigned short* u = (const unsigned short*)feat;
    int c = 0;
#pragma unroll
    for (int rep = 0; rep < 4; ++rep) {
        const int idx = threadIdx.x * 2 + rep * 512;
        const float v = fabsf(bf2f(u[idx]));
        c += (v > 1e-4f && v < 10.0f) ? 1 : 0;
    }
    atomicAdd(&cnt, c);
    __syncthreads();
    if (threadIdx.x == 0) *flag = (cnt > 512) ? 1 : 0;
}

// ================= CSR build: counting sort, zero global atomics =================
// Round-8/9: chunk 2048 (full grid resident), batched loads, packed 4B part
// entries ((col&255)|(row<<8); bucket id implied by segment).
#define CHUNK 2048

__global__ void __launch_bounds__(256) parta_hist(const int* __restrict__ col,
                                                  int* __restrict__ cntRB,
                                                  int E, int B, int NB) {
    __shared__ int h[512];
    for (int i = threadIdx.x; i < NB; i += 256) h[i] = 0;
    __syncthreads();
    const int base = blockIdx.x * CHUNK;
#pragma unroll
    for (int k = 0; k < CHUNK / 256; ++k) {
        const int e = base + k * 256 + threadIdx.x;
        if (e < E) atomicAdd(&h[col[e] >> 8], 1);
    }
    __syncthreads();
    for (int i = threadIdx.x; i < NB; i += 256) cntRB[i * B + blockIdx.x] = h[i];
}

__global__ void __launch_bounds__(256) scan_block_sums(const int* __restrict__ cnt,
                                                       int* __restrict__ bsum, int n) {
    __shared__ int red[256];
    const int base = blockIdx.x * 1024;
    int s = 0;
    for (int i = threadIdx.x; i < 1024; i += 256) {
        const int idx = base + i;
        s += (idx < n) ? cnt[idx] : 0;
    }
    red[threadIdx.x] = s;
    __syncthreads();
    for (int off = 128; off > 0; off >>= 1) {
        if (threadIdx.x < off) red[threadIdx.x] += red[threadIdx.x + off];
        __syncthreads();
    }
    if (threadIdx.x == 0) bsum[blockIdx.x] = red[0];
}

// single-block exclusive scan with carry loop — handles nb up to a few thousand
__global__ void __launch_bounds__(256) scan_bsum(int* __restrict__ bsum, int nb) {
    __shared__ int tmp[256];
    __shared__ int carry;
    const int x = threadIdx.x;
    if (x == 0) carry = 0;
    __syncthreads();
    for (int base = 0; base < nb; base += 256) {
        const int idx = base + x;
        const int v = (idx < nb) ? bsum[idx] : 0;
        tmp[x] = v;
        __syncthreads();
        int val = v;
        for (int off = 1; off < 256; off <<= 1) {
            const int t = (x >= off) ? tmp[x - off] : 0;
            __syncthreads();
            val += t;
            tmp[x] = val;
            __syncthreads();
        }
        if (idx < nb) bsum[idx] = carry + val - v;   // exclusive
        __syncthreads();                              // all read carry first
        if (x == 255) carry += val;                   // chunk total
        __syncthreads();
    }
}

__global__ void __launch_bounds__(256) scan_final(const int* __restrict__ cnt,
                                                  const int* __restrict__ bsum,
                                                  int* __restrict__ outp, int n) {
    __shared__ int tsum[256];
    const int base = blockIdx.x * 1024;
    const int x = threadIdx.x;
    int v[4];
    int s = 0;
#pragma unroll
    for (int k = 0; k < 4; ++k) {
        const int idx = base + x * 4 + k;
        v[k] = (idx < n) ? cnt[idx] : 0;
        s += v[k];
    }
    tsum[x] = s;
    __syncthreads();
    int val = s;
    for (int off = 1; off < 256; off <<= 1) {
        const int t = (x >= off) ? tsum[x - off] : 0;
        __syncthreads();
        val += t;
        tsum[x] = val;
        __syncthreads();
    }
    int prefix = bsum[blockIdx.x] + (val - s);
#pragma unroll
    for (int k = 0; k < 4; ++k) {
        const int idx = base + x * 4 + k;
        if (idx < n) outp[idx] = prefix;
        prefix += v[k];
    }
}

__global__ void __launch_bounds__(256) parta_scatter(const int* __restrict__ row,
                                                     const int* __restrict__ col,
                                                     const int* __restrict__ seg_off,
                                                     int* __restrict__ part,
                                                     int E, int B, int NB) {
    __shared__ int cur[512];
    for (int i = threadIdx.x; i < NB; i += 256) cur[i] = seg_off[i * B + blockIdx.x];
    __syncthreads();
    const int base = blockIdx.x * CHUNK;
    int c[CHUNK / 256], r[CHUNK / 256];
#pragma unroll
    for (int k = 0; k < CHUNK / 256; ++k) {
        const int e = base + k * 256 + threadIdx.x;
        if (e < E) { c[k] = col[e]; r[k] = row[e]; }
    }
#pragma unroll
    for (int k = 0; k < CHUNK / 256; ++k) {
        const int e = base + k * 256 + threadIdx.x;
        if (e < E) {
            const int p = atomicAdd(&cur[c[k] >> 8], 1);
            part[p] = (c[k] & 255) | (r[k] << 8);   // 4B packed: low8=col-in-bucket
        }
    }
}

__global__ void __launch_bounds__(512) csr_build(const int* __restrict__ part,
                                                 const int* __restrict__ seg_off,
                                                 int* __restrict__ rowptr,
                                                 int* __restrict__ cnt,
                                                 float* __restrict__ dinv,
                                                 int* __restrict__ csr,
                                                 int E, int B, int NB, int N) {
    __shared__ int cl[256];
    __shared__ int sc[256];
    const int r  = blockIdx.x;
    const int c0 = r << 8;
    const int s0 = seg_off[(size_t)r * B];
    const int s1 = (r == NB - 1) ? E : seg_off[(size_t)(r + 1) * B];
    const int x  = threadIdx.x;
    if (x < 256) cl[x] = 0;
    __syncthreads();
    for (int i = s0 + x; i < s1; i += 512)
        atomicAdd(&cl[part[i] & 255], 1);
    __syncthreads();
    int v = 0, val = 0;
    if (x < 256) { v = cl[x]; sc[x] = v; val = v; }
    __syncthreads();
    for (int off = 1; off < 256; off <<= 1) {
        const int t = (x >= off && x < 256) ? sc[x - off] : 0;
        __syncthreads();
        if (x < 256) { val += t; sc[x] = val; }
        __syncthreads();
    }
    const int excl = val - v;
    if (x < 256) {
        const int c = c0 + x;
        if (c < N) {
            rowptr[c] = s0 + excl;
            cnt[c]    = v;
            dinv[c]   = rsqrtf((float)v + 1.0f);
        }
        cl[x] = s0 + excl;   // reuse as cursor
    }
    __syncthreads();
    for (int i = s0 + x; i < s1; i += 512) {
        const int pr = part[i];
        const int p = atomicAdd(&cl[pr & 255], 1);
        csr[p] = (pr >> 8) << 7;   // row*128: byte offset template, shifted per layer
    }
}

// ================= MFMA GEMM: y = bf16((x @ W) * dinv[node]) =================
// Block = 4 waves x 16 nodes. Verified layouts (cdna docs m89/m91/m120):
//   A[m=lane&15][k=quad*8+j]   <- loaded straight from global (row node, k-chunk)
//   B[k=quad*8+j][n=lane&15]   <- ds_read_b128 from transposed Wt[n][k]
//   D col=lane&15, row=quad*4+reg
template<int F_IN, int F_OUT, int XMODE, int SPLIT>
__global__ void __launch_bounds__(256) gemm_mfma(const void* __restrict__ x,
                                                 const void* __restrict__ W,
                                                 const float* __restrict__ dinv,
                                                 unsigned short* __restrict__ ylo,
                                                 unsigned short* __restrict__ yhi,
                                                 int n, const int* __restrict__ flag) {
    constexpr int KS = F_IN / 32;        // k-slices
    constexpr int NT = F_OUT / 16;       // f-tiles
    constexpr int WPAD = F_IN + 8;       // +16B row pad vs bank conflicts
    const int isbf = *flag;
    __shared__ unsigned short Wt[F_OUT * WPAD];

    for (int i = threadIdx.x; i < F_IN * F_OUT; i += 256) {
        const int k = i / F_OUT, nn = i % F_OUT;
        Wt[nn * WPAD + k] = f2bfu(gload(W, i, isbf));
    }
    __syncthreads();

    const int lane = threadIdx.x & 63;
    const int wid  = threadIdx.x >> 6;
    const int m    = lane & 15;
    const int quad = lane >> 4;
    const int nodeA = blockIdx.x * 64 + wid * 16 + m;

    bf16x8 afr[KS];
    if (nodeA < n) {
        if (XMODE == 1 || isbf) {
            const unsigned short* xr = (const unsigned short*)x + (size_t)nodeA * F_IN;
#pragma unroll
            for (int s = 0; s < KS; ++s)
                afr[s] = *(const bf16x8*)(xr + s * 32 + quad * 8);
        } else {
            const float* xr = (const float*)x + (size_t)nodeA * F_IN;
#pragma unroll
            for (int s = 0; s < KS; ++s) {
                const float4 v0 = *(const float4*)(xr + s * 32 + quad * 8);
                const float4 v1 = *(const float4*)(xr + s * 32 + quad * 8 + 4);
                bf16x8 a;
                a[0] = (short)f2bfu(v0.x); a[1] = (short)f2bfu(v0.y);
                a[2] = (short)f2bfu(v0.z); a[3] = (short)f2bfu(v0.w);
                a[4] = (short)f2bfu(v1.x); a[5] = (short)f2bfu(v1.y);
                a[6] = (short)f2bfu(v1.z); a[7] = (short)f2bfu(v1.w);
                afr[s] = a;
            }
        }
    } else {
#pragma unroll
        for (int s = 0; s < KS; ++s) afr[s] = (bf16x8)(short)0;
    }

    f32x4 acc[NT];
#pragma unroll
    for (int t = 0; t < NT; ++t) acc[t] = (f32x4)0.f;

#pragma unroll
    for (int t = 0; t < NT; ++t) {
#pragma unroll
        for (int s = 0; s < KS; ++s) {
            const bf16x8 bfr = *(const bf16x8*)(Wt + (t * 16 + m) * WPAD + s * 32 + quad * 8);
            acc[t] = __builtin_amdgcn_mfma_f32_16x16x32_bf16(afr[s], bfr, acc[t], 0, 0, 0);
        }
    }

#pragma unroll
    for (int r = 0; r < 4; ++r) {
        const int ng = blockIdx.x * 64 + wid * 16 + quad * 4 + r;
        if (ng < n) {
            const float scl = dinv[ng];
#pragma unroll
            for (int t = 0; t < NT; ++t) {
                const int f = t * 16 + m;
                const unsigned short v = f2bfu(acc[t][r] * scl);
                if (SPLIT) {
                    if (t < NT / 2) ylo[(size_t)ng * (F_OUT / 2) + f] = v;
                    else            yhi[(size_t)ng * (F_OUT / 2) + f - F_OUT / 2] = v;
                } else {
                    ylo[(size_t)ng * F_OUT + f] = v;
                }
            }
        }
    }
}

// ---------- aggregate + fused epilogue ----------
// Round-9 redesign: ONE node per wave (uniform trip count, no inter-node
// divergence), EPW edges in flight across lane sub-groups, ushort2 gathers
// (4B/lane, full instruction efficiency; layer-1 rows = 128B = full line).
//   L   = F/2 lanes cover one row;  EPW = 64/L edges concurrent
//   lane = e*L + u : edge-slot e, feature pair (2u, 2u+1)
// Cross-e reduction = 1..3 shfl_xor at the end.
template<int F, int SH>
__global__ void __launch_bounds__(256) aggregate(const unsigned short* __restrict__ y,
                                                 const int* __restrict__ csr,
                                                 const int* __restrict__ rowptr,
                                                 const int* __restrict__ cnt,
                                                 const float* __restrict__ dinv,
                                                 const void* __restrict__ b,
                                                 unsigned short* __restrict__ out,
                                                 int n, int OSTR, int fofs,
                                                 const int* __restrict__ flag) {
    const int isbf = *flag;
    constexpr int L   = F / 2;      // lanes per edge-row
    constexpr int EPW = 64 / L;     // edges in flight per wave (2/4/8)
    constexpr int K   = 32 / EPW;   // per-lane gathers in the 32-edge chunk
    constexpr int K2  = 8 / EPW;    // per-lane gathers in the 8-edge chunk (>=1)
    const int lane = threadIdx.x & 63;
    const int node = blockIdx.x * 4 + (threadIdx.x >> 6);
    if (node >= n) return;
    const int e  = lane / L;
    const int u  = lane % L;
    const int ub = u * 4;           // byte offset of this lane's ushort2

    const int beg = rowptr[node];
    const int deg = cnt[node];
    const char* yb = (const char*)y;
    float ax = 0.f, ay = 0.f;
    int j = 0;
    for (; j + 32 <= deg; j += 32) {
        int o[K];
#pragma unroll
        for (int k = 0; k < K; ++k) o[k] = csr[beg + j + e + k * EPW] >> SH;
        float2 v[K];
#pragma unroll
        for (int k = 0; k < K; ++k) {
            const ushort2 t = *(const ushort2*)(yb + o[k] + ub);
            v[k] = make_float2(bf2f(t.x), bf2f(t.y));
        }
#pragma unroll
        for (int s = 1; s < K; s <<= 1)
#pragma unroll
            for (int k = 0; k < K; k += 2 * s) { v[k].x += v[k + s].x; v[k].y += v[k + s].y; }
        ax += v[0].x; ay += v[0].y;
    }
    for (; j + 8 <= deg; j += 8) {
        int o[K2];
#pragma unroll
        for (int k = 0; k < K2; ++k) o[k] = csr[beg + j + e + k * EPW] >> SH;
        float2 v[K2];
#pragma unroll
        for (int k = 0; k < K2; ++k) {
            const ushort2 t = *(const ushort2*)(yb + o[k] + ub);
            v[k] = make_float2(bf2f(t.x), bf2f(t.y));
        }
#pragma unroll
        for (int s = 1; s < K2; s <<= 1)
#pragma unroll
            for (int k = 0; k < K2; k += 2 * s) { v[k].x += v[k + s].x; v[k].y += v[k + s].y; }
        ax += v[0].x; ay += v[0].y;
    }
    for (; j < deg; j += EPW) {
        if (j + e < deg) {
            const int o = csr[beg + j + e] >> SH;
            const ushort2 t = *(const ushort2*)(yb + o + ub);
            ax += bf2f(t.x); ay += bf2f(t.y);
        }
    }

    // reduce across edge-slots (lanes differing in bits log2(L)..5)
#pragma unroll
    for (int mm = L; mm < 64; mm <<= 1) {
        ax += __shfl_xor(ax, mm, 64);
        ay += __shfl_xor(ay, mm, 64);
    }

    if (lane < L) {
        const ushort2 t = *(const ushort2*)(yb + (size_t)node * (F * 2) + ub);   // self term
        const float d  = dinv[node];
        const float rx = d * (ax + bf2f(t.x)) + gload(b, fofs + 2 * u, isbf);
        const float ry = d * (ay + bf2f(t.y)) + gload(b, fofs + 2 * u + 1, isbf);
        ushort2 w;
        w.x = f2bfu(fmaxf(rx, 0.f));
        w.y = f2bfu(fmaxf(ry, 0.f));
        *(ushort2*)((unsigned short*)out + (size_t)node * OSTR + fofs + 2 * u) = w;
    }
}

// ---------- dense head: out = relu(concat(f1,f2,f3) @ Wfc + bfc) ----------
__global__ void __launch_bounds__(256) head_kernel(const unsigned short* __restrict__ f1,
                                                   const unsigned short* __restrict__ f2,
                                                   const unsigned short* __restrict__ f3,
                                                   const void* __restrict__ Wfc,
                                                   const void* __restrict__ bfc,
                                                   void* __restrict__ out, int n,
                                                   const int* __restrict__ flag) {
    const int isbf = *flag;
    __shared__ float Ws[112 * 16];
    for (int i = threadIdx.x; i < 112 * 16; i += 256) Ws[i] = gload(Wfc, i, isbf);
    __syncthreads();

    const int h    = threadIdx.x & 3;
    const int node = blockIdx.x * 64 + (threadIdx.x >> 2);
    if (node >= n) return;

    float4 acc = make_float4(gload(bfc, 4 * h + 0, isbf), gload(bfc, 4 * h + 1, isbf),
                             gload(bfc, 4 * h + 2, isbf), gload(bfc, 4 * h + 3, isbf));

    const unsigned short* x1 = f1 + (size_t)node * 64;
#pragma unroll
    for (int k4 = 0; k4 < 16; ++k4) {
        const ushort4 xu = *(const ushort4*)(x1 + 4 * k4);
        const float xa[4] = {bf2f(xu.x), bf2f(xu.y), bf2f(xu.z), bf2f(xu.w)};
#pragma unroll
        for (int j = 0; j < 4; ++j) {
            const float4 wv = *(const float4*)(Ws + (4 * k4 + j) * 16 + 4 * h);
            acc.x = fmaf(xa[j], wv.x, acc.x); acc.y = fmaf(xa[j], wv.y, acc.y);
            acc.z = fmaf(xa[j], wv.z, acc.z); acc.w = fmaf(xa[j], wv.w, acc.w);
        }
    }
    const unsigned short* x2 = f2 + (size_t)node * 32;
#pragma unroll
    for (int k4 = 0; k4 < 8; ++k4) {
        const ushort4 xu = *(const ushort4*)(x2 + 4 * k4);
        const float xa[4] = {bf2f(xu.x), bf2f(xu.y), bf2f(xu.z), bf2f(xu.w)};
#pragma unroll
        for (int j = 0; j < 4; ++j) {
            const float4 wv = *(const float4*)(Ws + (64 + 4 * k4 + j) * 16 + 4 * h);
            acc.x = fmaf(xa[j], wv.x, acc.x); acc.y = fmaf(xa[j], wv.y, acc.y);
            acc.z = fmaf(xa[j], wv.z, acc.z); acc.w = fmaf(xa[j], wv.w, acc.w);
        }
    }
    const unsigned short* x3 = f3 + (size_t)node * 16;
#pragma unroll
    for (int k4 = 0; k4 < 4; ++k4) {
        const ushort4 xu = *(const ushort4*)(x3 + 4 * k4);
        const float xa[4] = {bf2f(xu.x), bf2f(xu.y), bf2f(xu.z), bf2f(xu.w)};
#pragma unroll
        for (int j = 0; j < 4; ++j) {
            const float4 wv = *(const float4*)(Ws + (96 + 4 * k4 + j) * 16 + 4 * h);
            acc.x = fmaf(xa[j], wv.x, acc.x); acc.y = fmaf(xa[j], wv.y, acc.y);
            acc.z = fmaf(xa[j], wv.z, acc.z); acc.w = fmaf(xa[j], wv.w, acc.w);
        }
    }

    const float4 r = make_float4(fmaxf(acc.x, 0.f), fmaxf(acc.y, 0.f),
                                 fmaxf(acc.z, 0.f), fmaxf(acc.w, 0.f));
    const size_t o = (size_t)node * 16 + 4 * h;
    if (isbf) {
        ushort4 u;
        u.x = f2bfu(r.x); u.y = f2bfu(r.y); u.z = f2bfu(r.z); u.w = f2bfu(r.w);
        *(ushort4*)((unsigned short*)out + o) = u;
    } else {
        *(float4*)((float*)out + o) = r;
    }
}

// ---------- launch ----------
extern "C" void kernel_launch(void* const* d_in, const int* in_sizes, int n_in,
                              void* d_out, int out_size, void* d_ws, size_t ws_size,
                              hipStream_t stream) {
    const int*  edges = (const int*)d_in[0];
    const void* feat  = d_in[1];
    const void* W1    = d_in[2];
    const void* b1    = d_in[3];
    const void* W2    = d_in[4];
    const void* b2    = d_in[5];
    const void* W3    = d_in[6];
    const void* b3    = d_in[7];
    const void* Wfc   = d_in[8];
    const void* bfc   = d_in[9];

    const int E = in_sizes[0] / 2;
    const int N = in_sizes[1] / 128;
    const int* row = edges;
    const int* col = edges + E;

    const int B  = DIVUP(E, CHUNK);    // phase-A blocks (2048-edge chunks, full-grid resident)
    const int NB = DIVUP(N, 256);      // col buckets / phase-B blocks
    const int NBB = NB * B;            // scan length

    char* p = (char*)d_ws;
    int*   flag   = (int*)p;               p += 16;
    float* dinv   = (float*)p;             p += (size_t)N * 4;
    int*   cnt    = (int*)p;               p += (size_t)N * 4;
    int*   rowptr = (int*)p;               p += (size_t)N * 4;
    int*   csr    = (int*)p;               p += (size_t)E * 4;
    int*   part   = (int*)p;               p += (size_t)E * 4;   // packed 4B entries
    unsigned short* y  = (unsigned short*)p; p += (size_t)N * 64 * 2;  // gemm output (max 64 feat)
    unsigned short* f1 = (unsigned short*)p; p += (size_t)N * 64 * 2;
    unsigned short* f2 = (unsigned short*)p; p += (size_t)N * 32 * 2;
    unsigned short* f3 = (unsigned short*)p; p += (size_t)N * 16 * 2;
    int*   cntRB  = (int*)p;               p += (size_t)NBB * 4;
    int*   segoff = (int*)p;               p += (size_t)NBB * 4;
    int*   bsum   = (int*)p;

    detect_dtype<<<1, 256, 0, stream>>>(feat, flag);

    // CSR build (also produces cnt, rowptr, dinv) — no global atomics
    parta_hist<<<B, 256, 0, stream>>>(col, cntRB, E, B, NB);
    const int nb = DIVUP(NBB, 1024);
    scan_block_sums<<<nb, 256, 0, stream>>>(cntRB, bsum, NBB);
    scan_bsum<<<1, 256, 0, stream>>>(bsum, nb);
    scan_final<<<nb, 256, 0, stream>>>(cntRB, bsum, segoff, NBB);
    parta_scatter<<<B, 256, 0, stream>>>(row, col, segoff, part, E, B, NB);
    csr_build<<<NB, 512, 0, stream>>>(part, segoff, rowptr, cnt, dinv, csr, E, B, NB, N);

    // layer 1: 128 -> 64, single full-width pass (rows = 128B = full line, SH=0)
    gemm_mfma<128, 64, 0, 0><<<DIVUP(N, 64), 256, 0, stream>>>(feat, W1, dinv, y, y, N, flag);
    aggregate<64, 0><<<DIVUP(N, 4), 256, 0, stream>>>(y, csr, rowptr, cnt, dinv, b1, f1, N, 64, 0, flag);

    // layer 2: 64 -> 32
    gemm_mfma<64, 32, 1, 0><<<DIVUP(N, 64), 256, 0, stream>>>(f1, W2, dinv, y, y, N, flag);
    aggregate<32, 1><<<DIVUP(N, 4), 256, 0, stream>>>(y, csr, rowptr, cnt, dinv, b2, f2, N, 32, 0, flag);

    // layer 3: 32 -> 16
    gemm_mfma<32, 16, 1, 0><<<DIVUP(N, 64), 256, 0, stream>>>(f2, W3, dinv, y, y, N, flag);
    aggregate<16, 2><<<DIVUP(N, 4), 256, 0, stream>>>(y, csr, rowptr, cnt, dinv, b3, f3, N, 16, 0, flag);

    // dense head
    head_kernel<<<DIVUP(N, 64), 256, 0, stream>>>(f1, f2, f3, Wfc, bfc, d_out, N, flag);
}

// Round 3
// 423.599 us; speedup vs baseline: 1.0587x; 1.0587x over previous
//
#include <hip/hip_runtime.h>
#include <hip/hip_bf16.h>

#define DIVUP(a, b) (((a) + (b) - 1) / (b))

typedef __attribute__((ext_vector_type(8))) short bf16x8;
typedef __attribute__((ext_vector_type(4))) float f32x4;

// ---------- helpers ----------
__device__ __forceinline__ float bf2f(unsigned short u) {
    union { unsigned int i; float f; } v;
    v.i = ((unsigned int)u) << 16;
    return v.f;
}
__device__ __forceinline__ unsigned short f2bfu(float x) {
    return __hip_bfloat16_raw(__float2bfloat16(x)).x;   // RNE
}
__device__ __forceinline__ float gload(const void* p, int i, int isbf) {
    return isbf ? bf2f(((const unsigned short*)p)[i]) : ((const float*)p)[i];
}

// ---------- dtype detection (round-1 note; f32 vs bf16 inputs) ----------
__global__ void __launch_bounds__(256) detect_dtype(const void* __restrict__ feat,
                                                    int* __restrict__ flag) {
    __shared__ int cnt;
    if (threadIdx.x == 0) cnt = 0;
    __syncthreads();
    const unsigned short* u = (const unsigned short*)feat;
    int c = 0;
#pragma unroll
    for (int rep = 0; rep < 4; ++rep) {
        const int idx = threadIdx.x * 2 + rep * 512;
        const float v = fabsf(bf2f(u[idx]));
        c += (v > 1e-4f && v < 10.0f) ? 1 : 0;
    }
    atomicAdd(&cnt, c);
    __syncthreads();
    if (threadIdx.x == 0) *flag = (cnt > 512) ? 1 : 0;
}

// ================= CSR build: counting sort, zero global atomics =================
// Round-8/9: chunk 2048 (full grid resident), batched loads, packed 4B part
// entries ((col&255)|(row<<8); bucket id implied by segment).
#define CHUNK 2048

__global__ void __launch_bounds__(256) parta_hist(const int* __restrict__ col,
                                                  int* __restrict__ cntRB,
                                                  int E, int B, int NB) {
    __shared__ int h[512];
    for (int i = threadIdx.x; i < NB; i += 256) h[i] = 0;
    __syncthreads();
    const int base = blockIdx.x * CHUNK;
#pragma unroll
    for (int k = 0; k < CHUNK / 256; ++k) {
        const int e = base + k * 256 + threadIdx.x;
        if (e < E) atomicAdd(&h[col[e] >> 8], 1);
    }
    __syncthreads();
    for (int i = threadIdx.x; i < NB; i += 256) cntRB[i * B + blockIdx.x] = h[i];
}

__global__ void __launch_bounds__(256) scan_block_sums(const int* __restrict__ cnt,
                                                       int* __restrict__ bsum, int n) {
    __shared__ int red[256];
    const int base = blockIdx.x * 1024;
    int s = 0;
    for (int i = threadIdx.x; i < 1024; i += 256) {
        const int idx = base + i;
        s += (idx < n) ? cnt[idx] : 0;
    }
    red[threadIdx.x] = s;
    __syncthreads();
    for (int off = 128; off > 0; off >>= 1) {
        if (threadIdx.x < off) red[threadIdx.x] += red[threadIdx.x + off];
        __syncthreads();
    }
    if (threadIdx.x == 0) bsum[blockIdx.x] = red[0];
}

// single-block exclusive scan with carry loop — handles nb up to a few thousand
__global__ void __launch_bounds__(256) scan_bsum(int* __restrict__ bsum, int nb) {
    __shared__ int tmp[256];
    __shared__ int carry;
    const int x = threadIdx.x;
    if (x == 0) carry = 0;
    __syncthreads();
    for (int base = 0; base < nb; base += 256) {
        const int idx = base + x;
        const int v = (idx < nb) ? bsum[idx] : 0;
        tmp[x] = v;
        __syncthreads();
        int val = v;
        for (int off = 1; off < 256; off <<= 1) {
            const int t = (x >= off) ? tmp[x - off] : 0;
            __syncthreads();
            val += t;
            tmp[x] = val;
            __syncthreads();
        }
        if (idx < nb) bsum[idx] = carry + val - v;   // exclusive
        __syncthreads();                              // all read carry first
        if (x == 255) carry += val;                   // chunk total
        __syncthreads();
    }
}

__global__ void __launch_bounds__(256) scan_final(const int* __restrict__ cnt,
                                                  const int* __restrict__ bsum,
                                                  int* __restrict__ outp, int n) {
    __shared__ int tsum[256];
    const int base = blockIdx.x * 1024;
    const int x = threadIdx.x;
    int v[4];
    int s = 0;
#pragma unroll
    for (int k = 0; k < 4; ++k) {
        const int idx = base + x * 4 + k;
        v[k] = (idx < n) ? cnt[idx] : 0;
        s += v[k];
    }
    tsum[x] = s;
    __syncthreads();
    int val = s;
    for (int off = 1; off < 256; off <<= 1) {
        const int t = (x >= off) ? tsum[x - off] : 0;
        __syncthreads();
        val += t;
        tsum[x] = val;
        __syncthreads();
    }
    int prefix = bsum[blockIdx.x] + (val - s);
#pragma unroll
    for (int k = 0; k < 4; ++k) {
        const int idx = base + x * 4 + k;
        if (idx < n) outp[idx] = prefix;
        prefix += v[k];
    }
}

__global__ void __launch_bounds__(256) parta_scatter(const int* __restrict__ row,
                                                     const int* __restrict__ col,
                                                     const int* __restrict__ seg_off,
                                                     int* __restrict__ part,
                                                     int E, int B, int NB) {
    __shared__ int cur[512];
    for (int i = threadIdx.x; i < NB; i += 256) cur[i] = seg_off[i * B + blockIdx.x];
    __syncthreads();
    const int base = blockIdx.x * CHUNK;
    int c[CHUNK / 256], r[CHUNK / 256];
#pragma unroll
    for (int k = 0; k < CHUNK / 256; ++k) {
        const int e = base + k * 256 + threadIdx.x;
        if (e < E) { c[k] = col[e]; r[k] = row[e]; }
    }
#pragma unroll
    for (int k = 0; k < CHUNK / 256; ++k) {
        const int e = base + k * 256 + threadIdx.x;
        if (e < E) {
            const int p = atomicAdd(&cur[c[k] >> 8], 1);
            part[p] = (c[k] & 255) | (r[k] << 8);   // 4B packed: low8=col-in-bucket
        }
    }
}

__global__ void __launch_bounds__(512) csr_build(const int* __restrict__ part,
                                                 const int* __restrict__ seg_off,
                                                 int* __restrict__ rowptr,
                                                 int* __restrict__ cnt,
                                                 float* __restrict__ dinv,
                                                 int* __restrict__ csr,
                                                 int E, int B, int NB, int N) {
    __shared__ int cl[256];
    __shared__ int sc[256];
    const int r  = blockIdx.x;
    const int c0 = r << 8;
    const int s0 = seg_off[(size_t)r * B];
    const int s1 = (r == NB - 1) ? E : seg_off[(size_t)(r + 1) * B];
    const int x  = threadIdx.x;
    if (x < 256) cl[x] = 0;
    __syncthreads();
    for (int i = s0 + x; i < s1; i += 512)
        atomicAdd(&cl[part[i] & 255], 1);
    __syncthreads();
    int v = 0, val = 0;
    if (x < 256) { v = cl[x]; sc[x] = v; val = v; }
    __syncthreads();
    for (int off = 1; off < 256; off <<= 1) {
        const int t = (x >= off && x < 256) ? sc[x - off] : 0;
        __syncthreads();
        if (x < 256) { val += t; sc[x] = val; }
        __syncthreads();
    }
    const int excl = val - v;
    if (x < 256) {
        const int c = c0 + x;
        if (c < N) {
            rowptr[c] = s0 + excl;
            cnt[c]    = v;
            dinv[c]   = rsqrtf((float)v + 1.0f);
        }
        cl[x] = s0 + excl;   // reuse as cursor
    }
    __syncthreads();
    for (int i = s0 + x; i < s1; i += 512) {
        const int pr = part[i];
        const int p = atomicAdd(&cl[pr & 255], 1);
        csr[p] = (pr >> 8) << 7;   // row*128: byte offset template, shifted per layer
    }
}

// ================= MFMA GEMM: y = bf16((x @ W) * dinv[node]) =================
// Block = 4 waves x 16 nodes. Verified layouts (cdna docs m89/m91/m120):
//   A[m=lane&15][k=quad*8+j]   <- loaded straight from global (row node, k-chunk)
//   B[k=quad*8+j][n=lane&15]   <- ds_read_b128 from transposed Wt[n][k]
//   D col=lane&15, row=quad*4+reg
template<int F_IN, int F_OUT, int XMODE, int SPLIT>
__global__ void __launch_bounds__(256) gemm_mfma(const void* __restrict__ x,
                                                 const void* __restrict__ W,
                                                 const float* __restrict__ dinv,
                                                 unsigned short* __restrict__ ylo,
                                                 unsigned short* __restrict__ yhi,
                                                 int n, const int* __restrict__ flag) {
    constexpr int KS = F_IN / 32;        // k-slices
    constexpr int NT = F_OUT / 16;       // f-tiles
    constexpr int WPAD = F_IN + 8;       // +16B row pad vs bank conflicts
    const int isbf = *flag;
    __shared__ unsigned short Wt[F_OUT * WPAD];

    for (int i = threadIdx.x; i < F_IN * F_OUT; i += 256) {
        const int k = i / F_OUT, nn = i % F_OUT;
        Wt[nn * WPAD + k] = f2bfu(gload(W, i, isbf));
    }
    __syncthreads();

    const int lane = threadIdx.x & 63;
    const int wid  = threadIdx.x >> 6;
    const int m    = lane & 15;
    const int quad = lane >> 4;
    const int nodeA = blockIdx.x * 64 + wid * 16 + m;

    bf16x8 afr[KS];
    if (nodeA < n) {
        if (XMODE == 1 || isbf) {
            const unsigned short* xr = (const unsigned short*)x + (size_t)nodeA * F_IN;
#pragma unroll
            for (int s = 0; s < KS; ++s)
                afr[s] = *(const bf16x8*)(xr + s * 32 + quad * 8);
        } else {
            const float* xr = (const float*)x + (size_t)nodeA * F_IN;
#pragma unroll
            for (int s = 0; s < KS; ++s) {
                const float4 v0 = *(const float4*)(xr + s * 32 + quad * 8);
                const float4 v1 = *(const float4*)(xr + s * 32 + quad * 8 + 4);
                bf16x8 a;
                a[0] = (short)f2bfu(v0.x); a[1] = (short)f2bfu(v0.y);
                a[2] = (short)f2bfu(v0.z); a[3] = (short)f2bfu(v0.w);
                a[4] = (short)f2bfu(v1.x); a[5] = (short)f2bfu(v1.y);
                a[6] = (short)f2bfu(v1.z); a[7] = (short)f2bfu(v1.w);
                afr[s] = a;
            }
        }
    } else {
#pragma unroll
        for (int s = 0; s < KS; ++s) afr[s] = (bf16x8)(short)0;
    }

    f32x4 acc[NT];
#pragma unroll
    for (int t = 0; t < NT; ++t) acc[t] = (f32x4)0.f;

#pragma unroll
    for (int t = 0; t < NT; ++t) {
#pragma unroll
        for (int s = 0; s < KS; ++s) {
            const bf16x8 bfr = *(const bf16x8*)(Wt + (t * 16 + m) * WPAD + s * 32 + quad * 8);
            acc[t] = __builtin_amdgcn_mfma_f32_16x16x32_bf16(afr[s], bfr, acc[t], 0, 0, 0);
        }
    }

#pragma unroll
    for (int r = 0; r < 4; ++r) {
        const int ng = blockIdx.x * 64 + wid * 16 + quad * 4 + r;
        if (ng < n) {
            const float scl = dinv[ng];
#pragma unroll
            for (int t = 0; t < NT; ++t) {
                const int f = t * 16 + m;
                const unsigned short v = f2bfu(acc[t][r] * scl);
                if (SPLIT) {
                    if (t < NT / 2) ylo[(size_t)ng * (F_OUT / 2) + f] = v;
                    else            yhi[(size_t)ng * (F_OUT / 2) + f - F_OUT / 2] = v;
                } else {
                    ylo[(size_t)ng * F_OUT + f] = v;
                }
            }
        }
    }
}

// ---------- aggregate + fused epilogue ----------
// Round-10: decouple MLP from F. Every node-group = 2 edge-slots x L lanes
// (EPW=2 fixed), NPW = 64/F nodes per wave. ALL layers run K=16 outstanding
// ushort2 gathers/lane in the 32-chunk (round-9 regression: K scaled down
// with F -> L3 layer had only 4 in flight; gather is latency-bound so flight
// depth is the controlling variable). 16-chunk (K=8) added for mid degrees.
template<int F, int SH>
__global__ void __launch_bounds__(256) aggregate(const unsigned short* __restrict__ y,
                                                 const int* __restrict__ csr,
                                                 const int* __restrict__ rowptr,
                                                 const int* __restrict__ cnt,
                                                 const float* __restrict__ dinv,
                                                 const void* __restrict__ b,
                                                 unsigned short* __restrict__ out,
                                                 int n, int OSTR, int fofs,
                                                 const int* __restrict__ flag) {
    const int isbf = *flag;
    constexpr int L   = F / 2;        // lanes per row (ushort2 each)
    constexpr int GL  = 2 * L;        // lanes per node-group (2 edge slots)
    constexpr int NPW = 64 / GL;      // nodes per wave
    constexpr int LGL = (GL == 64) ? 6 : (GL == 32) ? 5 : 4;
    const int lane = threadIdx.x & 63;
    const int wv   = (blockIdx.x * 256 + threadIdx.x) >> 6;
    const int node = wv * NPW + (lane >> LGL);
    if (node >= n) return;
    const int g  = lane & (GL - 1);
    const int e  = g >> (LGL - 1);    // edge slot 0/1
    const int u  = g & (L - 1);       // feature pair index
    const int ub = u * 4;             // byte offset of this lane's ushort2

    const int beg = rowptr[node];
    const int deg = cnt[node];
    const char* yb = (const char*)y;
    float ax = 0.f, ay = 0.f;
    int j = 0;
    for (; j + 32 <= deg; j += 32) {
        int o[16];
#pragma unroll
        for (int k = 0; k < 16; ++k) o[k] = csr[beg + j + e + 2 * k] >> SH;
        float2 v[16];
#pragma unroll
        for (int k = 0; k < 16; ++k) {
            const ushort2 t = *(const ushort2*)(yb + o[k] + ub);
            v[k] = make_float2(bf2f(t.x), bf2f(t.y));
        }
#pragma unroll
        for (int s = 1; s < 16; s <<= 1)
#pragma unroll
            for (int k = 0; k < 16; k += 2 * s) { v[k].x += v[k + s].x; v[k].y += v[k + s].y; }
        ax += v[0].x; ay += v[0].y;
    }
    if (j + 16 <= deg) {
        int o[8];
#pragma unroll
        for (int k = 0; k < 8; ++k) o[k] = csr[beg + j + e + 2 * k] >> SH;
        float2 v[8];
#pragma unroll
        for (int k = 0; k < 8; ++k) {
            const ushort2 t = *(const ushort2*)(yb + o[k] + ub);
            v[k] = make_float2(bf2f(t.x), bf2f(t.y));
        }
#pragma unroll
        for (int s = 1; s < 8; s <<= 1)
#pragma unroll
            for (int k = 0; k < 8; k += 2 * s) { v[k].x += v[k + s].x; v[k].y += v[k + s].y; }
        ax += v[0].x; ay += v[0].y;
        j += 16;
    }
    if (j + 8 <= deg) {
        int o[4];
#pragma unroll
        for (int k = 0; k < 4; ++k) o[k] = csr[beg + j + e + 2 * k] >> SH;
        float2 v[4];
#pragma unroll
        for (int k = 0; k < 4; ++k) {
            const ushort2 t = *(const ushort2*)(yb + o[k] + ub);
            v[k] = make_float2(bf2f(t.x), bf2f(t.y));
        }
#pragma unroll
        for (int s = 1; s < 4; s <<= 1)
#pragma unroll
            for (int k = 0; k < 4; k += 2 * s) { v[k].x += v[k + s].x; v[k].y += v[k + s].y; }
        ax += v[0].x; ay += v[0].y;
        j += 8;
    }
    for (; j < deg; j += 2) {
        if (j + e < deg) {
            const int o = csr[beg + j + e] >> SH;
            const ushort2 t = *(const ushort2*)(yb + o + ub);
            ax += bf2f(t.x); ay += bf2f(t.y);
        }
    }

    // reduce across the 2 edge-slots (partner is same node -> same exec state)
    ax += __shfl_xor(ax, L, 64);
    ay += __shfl_xor(ay, L, 64);

    if (g < L) {
        const ushort2 t = *(const ushort2*)(yb + (size_t)node * (F * 2) + ub);   // self term
        const float d  = dinv[node];
        const float rx = d * (ax + bf2f(t.x)) + gload(b, fofs + 2 * u, isbf);
        const float ry = d * (ay + bf2f(t.y)) + gload(b, fofs + 2 * u + 1, isbf);
        ushort2 w;
        w.x = f2bfu(fmaxf(rx, 0.f));
        w.y = f2bfu(fmaxf(ry, 0.f));
        *(ushort2*)((unsigned short*)out + (size_t)node * OSTR + fofs + 2 * u) = w;
    }
}

// ---------- dense head: out = relu(concat(f1,f2,f3) @ Wfc + bfc) ----------
__global__ void __launch_bounds__(256) head_kernel(const unsigned short* __restrict__ f1,
                                                   const unsigned short* __restrict__ f2,
                                                   const unsigned short* __restrict__ f3,
                                                   const void* __restrict__ Wfc,
                                                   const void* __restrict__ bfc,
                                                   void* __restrict__ out, int n,
                                                   const int* __restrict__ flag) {
    const int isbf = *flag;
    __shared__ float Ws[112 * 16];
    for (int i = threadIdx.x; i < 112 * 16; i += 256) Ws[i] = gload(Wfc, i, isbf);
    __syncthreads();

    const int h    = threadIdx.x & 3;
    const int node = blockIdx.x * 64 + (threadIdx.x >> 2);
    if (node >= n) return;

    float4 acc = make_float4(gload(bfc, 4 * h + 0, isbf), gload(bfc, 4 * h + 1, isbf),
                             gload(bfc, 4 * h + 2, isbf), gload(bfc, 4 * h + 3, isbf));

    const unsigned short* x1 = f1 + (size_t)node * 64;
#pragma unroll
    for (int k4 = 0; k4 < 16; ++k4) {
        const ushort4 xu = *(const ushort4*)(x1 + 4 * k4);
        const float xa[4] = {bf2f(xu.x), bf2f(xu.y), bf2f(xu.z), bf2f(xu.w)};
#pragma unroll
        for (int j = 0; j < 4; ++j) {
            const float4 wv = *(const float4*)(Ws + (4 * k4 + j) * 16 + 4 * h);
            acc.x = fmaf(xa[j], wv.x, acc.x); acc.y = fmaf(xa[j], wv.y, acc.y);
            acc.z = fmaf(xa[j], wv.z, acc.z); acc.w = fmaf(xa[j], wv.w, acc.w);
        }
    }
    const unsigned short* x2 = f2 + (size_t)node * 32;
#pragma unroll
    for (int k4 = 0; k4 < 8; ++k4) {
        const ushort4 xu = *(const ushort4*)(x2 + 4 * k4);
        const float xa[4] = {bf2f(xu.x), bf2f(xu.y), bf2f(xu.z), bf2f(xu.w)};
#pragma unroll
        for (int j = 0; j < 4; ++j) {
            const float4 wv = *(const float4*)(Ws + (64 + 4 * k4 + j) * 16 + 4 * h);
            acc.x = fmaf(xa[j], wv.x, acc.x); acc.y = fmaf(xa[j], wv.y, acc.y);
            acc.z = fmaf(xa[j], wv.z, acc.z); acc.w = fmaf(xa[j], wv.w, acc.w);
        }
    }
    const unsigned short* x3 = f3 + (size_t)node * 16;
#pragma unroll
    for (int k4 = 0; k4 < 4; ++k4) {
        const ushort4 xu = *(const ushort4*)(x3 + 4 * k4);
        const float xa[4] = {bf2f(xu.x), bf2f(xu.y), bf2f(xu.z), bf2f(xu.w)};
#pragma unroll
        for (int j = 0; j < 4; ++j) {
            const float4 wv = *(const float4*)(Ws + (96 + 4 * k4 + j) * 16 + 4 * h);
            acc.x = fmaf(xa[j], wv.x, acc.x); acc.y = fmaf(xa[j], wv.y, acc.y);
            acc.z = fmaf(xa[j], wv.z, acc.z); acc.w = fmaf(xa[j], wv.w, acc.w);
        }
    }

    const float4 r = make_float4(fmaxf(acc.x, 0.f), fmaxf(acc.y, 0.f),
                                 fmaxf(acc.z, 0.f), fmaxf(acc.w, 0.f));
    const size_t o = (size_t)node * 16 + 4 * h;
    if (isbf) {
        ushort4 u;
        u.x = f2bfu(r.x); u.y = f2bfu(r.y); u.z = f2bfu(r.z); u.w = f2bfu(r.w);
        *(ushort4*)((unsigned short*)out + o) = u;
    } else {
        *(float4*)((float*)out + o) = r;
    }
}

// ---------- launch ----------
extern "C" void kernel_launch(void* const* d_in, const int* in_sizes, int n_in,
                              void* d_out, int out_size, void* d_ws, size_t ws_size,
                              hipStream_t stream) {
    const int*  edges = (const int*)d_in[0];
    const void* feat  = d_in[1];
    const void* W1    = d_in[2];
    const void* b1    = d_in[3];
    const void* W2    = d_in[4];
    const void* b2    = d_in[5];
    const void* W3    = d_in[6];
    const void* b3    = d_in[7];
    const void* Wfc   = d_in[8];
    const void* bfc   = d_in[9];

    const int E = in_sizes[0] / 2;
    const int N = in_sizes[1] / 128;
    const int* row = edges;
    const int* col = edges + E;

    const int B  = DIVUP(E, CHUNK);    // phase-A blocks (2048-edge chunks, full-grid resident)
    const int NB = DIVUP(N, 256);      // col buckets / phase-B blocks
    const int NBB = NB * B;            // scan length

    char* p = (char*)d_ws;
    int*   flag   = (int*)p;               p += 16;
    float* dinv   = (float*)p;             p += (size_t)N * 4;
    int*   cnt    = (int*)p;               p += (size_t)N * 4;
    int*   rowptr = (int*)p;               p += (size_t)N * 4;
    int*   csr    = (int*)p;               p += (size_t)E * 4;
    int*   part   = (int*)p;               p += (size_t)E * 4;   // packed 4B entries
    unsigned short* y  = (unsigned short*)p; p += (size_t)N * 64 * 2;  // gemm output (max 64 feat)
    unsigned short* f1 = (unsigned short*)p; p += (size_t)N * 64 * 2;
    unsigned short* f2 = (unsigned short*)p; p += (size_t)N * 32 * 2;
    unsigned short* f3 = (unsigned short*)p; p += (size_t)N * 16 * 2;
    int*   cntRB  = (int*)p;               p += (size_t)NBB * 4;
    int*   segoff = (int*)p;               p += (size_t)NBB * 4;
    int*   bsum   = (int*)p;

    detect_dtype<<<1, 256, 0, stream>>>(feat, flag);

    // CSR build (also produces cnt, rowptr, dinv) — no global atomics
    parta_hist<<<B, 256, 0, stream>>>(col, cntRB, E, B, NB);
    const int nb = DIVUP(NBB, 1024);
    scan_block_sums<<<nb, 256, 0, stream>>>(cntRB, bsum, NBB);
    scan_bsum<<<1, 256, 0, stream>>>(bsum, nb);
    scan_final<<<nb, 256, 0, stream>>>(cntRB, bsum, segoff, NBB);
    parta_scatter<<<B, 256, 0, stream>>>(row, col, segoff, part, E, B, NB);
    csr_build<<<NB, 512, 0, stream>>>(part, segoff, rowptr, cnt, dinv, csr, E, B, NB, N);

    // layer 1: 128 -> 64, single full-width pass (rows = 128B = full line, SH=0)
    gemm_mfma<128, 64, 0, 0><<<DIVUP(N, 64), 256, 0, stream>>>(feat, W1, dinv, y, y, N, flag);
    aggregate<64, 0><<<DIVUP(N, 4), 256, 0, stream>>>(y, csr, rowptr, cnt, dinv, b1, f1, N, 64, 0, flag);

    // layer 2: 64 -> 32  (2 nodes/wave)
    gemm_mfma<64, 32, 1, 0><<<DIVUP(N, 64), 256, 0, stream>>>(f1, W2, dinv, y, y, N, flag);
    aggregate<32, 1><<<DIVUP(N, 8), 256, 0, stream>>>(y, csr, rowptr, cnt, dinv, b2, f2, N, 32, 0, flag);

    // layer 3: 32 -> 16  (4 nodes/wave)
    gemm_mfma<32, 16, 1, 0><<<DIVUP(N, 64), 256, 0, stream>>>(f2, W3, dinv, y, y, N, flag);
    aggregate<16, 2><<<DIVUP(N, 16), 256, 0, stream>>>(y, csr, rowptr, cnt, dinv, b3, f3, N, 16, 0, flag);

    // dense head
    head_kernel<<<DIVUP(N, 64), 256, 0, stream>>>(f1, f2, f3, Wfc, bfc, d_out, N, flag);
}